// Round 11
// baseline (202.305 us; speedup 1.0000x reference)
//
#include <hip/hip_runtime.h>
#include <stdint.h>

// BertSelfAttentionWithRelation  B=4 L=512 H=12 D=64 HIDDEN=768
// Round 11: R10 + m97-style k_qkv_gemm (128x128 tile, BK=64,
//   global_load_lds dwordx4 staging w/ pre-swizzled source, 32 MFMA/K-step).
//   All other kernels identical to R10 (best: 181.0 us).

typedef __attribute__((ext_vector_type(8))) short bf16x8;
typedef __attribute__((ext_vector_type(4))) float f32x4;
typedef __attribute__((ext_vector_type(4))) unsigned int u32x4;
typedef __attribute__((ext_vector_type(2))) unsigned int u32x2;

__device__ __forceinline__ unsigned short f2bf(float f) {
  union { float f; unsigned int u; } v; v.f = f;
  unsigned int r = v.u + 0x7fffu + ((v.u >> 16) & 1u);
  return (unsigned short)(r >> 16);
}
__device__ __forceinline__ float bf2f(unsigned short s) {
  union { unsigned int u; float f; } v; v.u = ((unsigned int)s) << 16;
  return v.f;
}
__device__ __forceinline__ void lds_barrier() {
  asm volatile("s_waitcnt lgkmcnt(0)\ns_barrier" ::: "memory");
}
__device__ __forceinline__ unsigned cvtpk(float lo, float hi) {
  unsigned r;
  asm("v_cvt_pk_bf16_f32 %0, %1, %2" : "=v"(r) : "v"(lo), "v"(hi));
  return r;
}
__device__ __forceinline__ void gload_lds16(const void* g, void* l) {
  __builtin_amdgcn_global_load_lds((const __attribute__((address_space(1))) void*)g,
                                   (__attribute__((address_space(3))) void*)l, 16, 0, 0);
}

#define GL16(dst, addr, OFF)                                                  \
  asm volatile("global_load_dwordx4 %0, %1, off offset:" #OFF                \
               : "=v"(dst) : "v"(addr))
#define WAITV(N)                                                              \
  do {                                                                        \
    asm volatile("s_waitcnt vmcnt(" #N ")" ::: "memory");                     \
    __builtin_amdgcn_sched_barrier(0);                                        \
  } while (0)

// ---------------- K0: merged hidden cvt + W transpose ----------------
__global__ void k_prep(const float* __restrict__ hidden,
                       const float* __restrict__ Wq, const float* __restrict__ Wk,
                       const float* __restrict__ Wv,
                       unsigned short* __restrict__ hb,
                       unsigned short* __restrict__ wt) {
  __shared__ float t[64][65];
  const int bid = blockIdx.x;
  if (bid >= 432) {
    int i = (bid - 432) * 256 + threadIdx.x;
    float4 v = reinterpret_cast<const float4*>(hidden)[i];
    ushort4 o;
    o.x = f2bf(v.x); o.y = f2bf(v.y); o.z = f2bf(v.z); o.w = f2bf(v.w);
    reinterpret_cast<ushort4*>(hb)[i] = o;
    return;
  }
  const int wsel = bid / 144, rem = bid % 144;
  const int kt = rem / 12, nt = rem % 12;
  const float* W = wsel == 0 ? Wq : (wsel == 1 ? Wk : Wv);
  const int lx = threadIdx.x & 63, ly = threadIdx.x >> 6;
  for (int i = 0; i < 64; i += 4)
    t[ly + i][lx] = W[(size_t)(kt * 64 + ly + i) * 768 + nt * 64 + lx];
  __syncthreads();
  for (int i = 0; i < 64; i += 4) {
    int r = ly + i;
    wt[((size_t)wsel * 768 + nt * 64 + r) * 768 + kt * 64 + lx] = f2bf(t[lx][r]);
  }
}

// ---------------- K1: fused QKV GEMM, 128x128 tile + global_load_lds ------
__global__ __launch_bounds__(256) void k_qkv_gemm(
    const unsigned short* __restrict__ A,   // [2048][768] bf16
    const unsigned short* __restrict__ Bt,  // [2304][768] bf16
    const float* __restrict__ bq, const float* __restrict__ bk, const float* __restrict__ bv,
    unsigned short* __restrict__ qbf, unsigned short* __restrict__ kbf,
    unsigned short* __restrict__ vbt) {
  __shared__ __align__(16) char lA[16384];   // [128 m][64 k] bf16, swizzled
  __shared__ __align__(16) char lB[16384];   // [128 n][64 k] bf16, swizzled
  const int tid = threadIdx.x, lane = tid & 63, w = tid >> 6;
  const int lm = lane & 15, lg = lane >> 4;
  const int m0 = blockIdx.x * 128, n0 = blockIdx.y * 128;
  const int wm = (w >> 1) * 64, wn = (w & 1) * 64;
  f32x4 acc[4][4] = {};

  for (int kt = 0; kt < 12; ++kt) {
    __syncthreads();   // readers of previous tile done
    // stage: linear LDS dest (wave-uniform base + lane*16), pre-swizzled src
#pragma unroll
    for (int i = 0; i < 4; ++i) {
      int slot = i * 256 + tid;        // 16B units, 0..1023 (128 rows x 8)
      int row = slot >> 3, x = slot & 7;
      int sw = (x * 16) ^ ((row & 7) << 4);
      gload_lds16((const char*)A + (size_t)(m0 + row) * 1536 + kt * 128 + sw,
                  lA + (size_t)(i * 256 + w * 64) * 16);
      gload_lds16((const char*)Bt + (size_t)(n0 + row) * 1536 + kt * 128 + sw,
                  lB + (size_t)(i * 256 + w * 64) * 16);
    }
    __syncthreads();   // staging landed (vmcnt drained by barrier)
#pragma unroll
    for (int ks = 0; ks < 2; ++ks) {
      bf16x8 fa[4], fb[4];
      const int kb = ks * 64 + lg * 16;
#pragma unroll
      for (int mi = 0; mi < 4; ++mi) {
        int row = wm + mi * 16 + lm;
        fa[mi] = *(const bf16x8*)(lA + row * 128 + (kb ^ ((row & 7) << 4)));
      }
#pragma unroll
      for (int ni = 0; ni < 4; ++ni) {
        int row = wn + ni * 16 + lm;
        fb[ni] = *(const bf16x8*)(lB + row * 128 + (kb ^ ((row & 7) << 4)));
      }
#pragma unroll
      for (int mi = 0; mi < 4; ++mi)
#pragma unroll
        for (int ni = 0; ni < 4; ++ni)
          acc[mi][ni] = __builtin_amdgcn_mfma_f32_16x16x32_bf16(fa[mi], fb[ni], acc[mi][ni], 0, 0, 0);
    }
  }
  // epilogue: C/D col=lane&15, row=(lane>>4)*4+r; route to q/k/v buffers
#pragma unroll
  for (int mi = 0; mi < 4; ++mi)
#pragma unroll
    for (int ni = 0; ni < 4; ++ni) {
      int gn = n0 + wn + ni * 16 + lm;
      float bias = (gn < 768) ? bq[gn] : (gn < 1536 ? bk[gn - 768] : bv[gn - 1536]);
#pragma unroll
      for (int r = 0; r < 4; ++r) {
        int gm = m0 + wm + mi * 16 + (lg << 2) + r;
        float val = acc[mi][ni][r] + bias;
        int b = gm >> 9, l = gm & 511;
        int d = gn & 63;
        if (gn < 768) {
          int h = gn >> 6;
          qbf[(((size_t)(b * 12 + h)) * 512 + l) * 64 + d] = f2bf(val);
        } else if (gn < 1536) {
          int h = (gn - 768) >> 6;
          kbf[(((size_t)(b * 12 + h)) * 512 + l) * 64 + d] = f2bf(val);
        } else {
          int h = (gn - 1536) >> 6;
          vbt[(((size_t)(b * 12 + h)) * 64 + d) * 512 + l] = f2bf(val);
        }
      }
    }
}

// ---------------- K2a: content scores S = q.k^T per (b,h), bf16 out -------
__global__ __launch_bounds__(256) void k_scores(
    const unsigned short* __restrict__ qbf, const unsigned short* __restrict__ kbf,
    unsigned short* __restrict__ Sb) {
  __shared__ __align__(16) unsigned short lQ[64 * 64];
  __shared__ __align__(16) unsigned short lK[64 * 64];
  const int tid = threadIdx.x, lane = tid & 63, w = tid >> 6;
  const int mt = blockIdx.x, lt = blockIdx.y, bh = blockIdx.z;
  const int wm = (w >> 1) * 32, wn = (w & 1) * 32;
  f32x4 acc[2][2] = {};
#pragma unroll
  for (int i = 0; i < 2; ++i) {
    int e16 = i * 256 + tid;
    int row = e16 >> 3;
    int kb = (e16 & 7) * 16;
    int dst = row * 128 + (kb ^ ((row & 7) << 4));
    u32x4 vq = *(const u32x4*)((const char*)qbf + ((size_t)bh * 512 + lt * 64 + row) * 128 + kb);
    *(u32x4*)((char*)lQ + dst) = vq;
    u32x4 vk = *(const u32x4*)((const char*)kbf + ((size_t)bh * 512 + mt * 64 + row) * 128 + kb);
    *(u32x4*)((char*)lK + dst) = vk;
  }
  __syncthreads();
#pragma unroll
  for (int ks = 0; ks < 2; ++ks) {
    bf16x8 fa[2], fb[2];
    const int kbyte = (ks * 32 + (lane >> 4) * 8) * 2;
#pragma unroll
    for (int mi = 0; mi < 2; ++mi) {
      int row = wm + mi * 16 + (lane & 15);
      fa[mi] = *(const bf16x8*)((const char*)lQ + row * 128 + (kbyte ^ ((row & 7) << 4)));
    }
#pragma unroll
    for (int ni = 0; ni < 2; ++ni) {
      int row = wn + ni * 16 + (lane & 15);
      fb[ni] = *(const bf16x8*)((const char*)lK + row * 128 + (kbyte ^ ((row & 7) << 4)));
    }
#pragma unroll
    for (int mi = 0; mi < 2; ++mi)
#pragma unroll
      for (int ni = 0; ni < 2; ++ni)
        acc[mi][ni] = __builtin_amdgcn_mfma_f32_16x16x32_bf16(fa[mi], fb[ni], acc[mi][ni], 0, 0, 0);
  }
#pragma unroll
  for (int mi = 0; mi < 2; ++mi)
#pragma unroll
    for (int ni = 0; ni < 2; ++ni) {
      int gm = mt * 64 + wn + ni * 16 + (lane & 15);
#pragma unroll
      for (int r = 0; r < 4; ++r) {
        int gl = lt * 64 + wm + mi * 16 + ((lane >> 4) << 2) + r;
        Sb[(size_t)bh * 262144 + (size_t)gl * 512 + gm] = f2bf(acc[mi][ni][r]);
      }
    }
}

// ---------------- K2b: rel-K scores + softmax -> pbf, one block per (b,l) --
__global__ __launch_bounds__(256, 5) void k_relA(
    const unsigned short* __restrict__ qbf,
    const float* __restrict__ relk,   // [B][L][L][D]  (b, l, r, d)
    const unsigned short* __restrict__ Sb,
    unsigned short* __restrict__ pbf) {
  __shared__ __align__(16) char X[12288];
  const int tid = threadIdx.x, lane = tid & 63, w = tid >> 6;
  const int bl = blockIdx.x, b = bl >> 9, l = bl & 511;
  const int lm = lane & 15, lg = lane >> 4;
  const int hq = lm < 12 ? lm : 11;

  union { f32x4 f; bf16x8 b; } qa0, qa1;
  const char* aQ = (const char*)qbf + (((size_t)b * 12 + hq) * 512 + l) * 128 + (size_t)lg * 16;
  GL16(qa0.f, aQ, 0);
  GL16(qa1.f, aQ, 64);

  const char* aA = (const char*)relk + (size_t)bl * 131072 +
                   (size_t)(w * 128 + lm) * 256 + (size_t)lg * 32;
  f32x4 td[3][4];
#define TISSUE(t, s)                                                          \
  do {                                                                        \
    const char* p_ = aA + (size_t)(t) * 4096;                                 \
    GL16(td[s][0], p_, 0);   GL16(td[s][1], p_, 16);                          \
    GL16(td[s][2], p_, 128); GL16(td[s][3], p_, 144);                         \
  } while (0)
#define ACONSUME(t, s)                                                        \
  do {                                                                        \
    union { bf16x8 v; unsigned u[4]; } fb0, fb1;                              \
    fb0.u[0] = cvtpk(td[s][0][0], td[s][0][1]);                               \
    fb0.u[1] = cvtpk(td[s][0][2], td[s][0][3]);                               \
    fb0.u[2] = cvtpk(td[s][1][0], td[s][1][1]);                               \
    fb0.u[3] = cvtpk(td[s][1][2], td[s][1][3]);                               \
    fb1.u[0] = cvtpk(td[s][2][0], td[s][2][1]);                               \
    fb1.u[1] = cvtpk(td[s][2][2], td[s][2][3]);                               \
    fb1.u[2] = cvtpk(td[s][3][0], td[s][3][1]);                               \
    fb1.u[3] = cvtpk(td[s][3][2], td[s][3][3]);                               \
    f32x4 acc = {0.f, 0.f, 0.f, 0.f};                                         \
    acc = __builtin_amdgcn_mfma_f32_16x16x32_bf16(qa0.b, fb0.v, acc, 0, 0, 0);\
    acc = __builtin_amdgcn_mfma_f32_16x16x32_bf16(qa1.b, fb1.v, acc, 0, 0, 0);\
    if (lg < 3) {                                                             \
      const int r_ = w * 128 + (t) * 16 + lm;                                 \
      _Pragma("unroll")                                                       \
      for (int reg = 0; reg < 4; ++reg) {                                     \
        const int h_ = lg * 4 + reg;                                          \
        *(unsigned short*)(X + h_ * 1024 +                                    \
                           ((r_ * 2) ^ (((h_ >> 2) & 3) << 5))) =             \
            f2bf(acc[reg]);                                                   \
      }                                                                       \
    }                                                                         \
  } while (0)

  TISSUE(0, 0); TISSUE(1, 1); TISSUE(2, 2);
  WAITV(8); ACONSUME(0, 0); TISSUE(3, 0);
  WAITV(8); ACONSUME(1, 1); TISSUE(4, 1);
  WAITV(8); ACONSUME(2, 2); TISSUE(5, 2);
  WAITV(8); ACONSUME(3, 0); TISSUE(6, 0);
  WAITV(8); ACONSUME(4, 1); TISSUE(7, 1);
  WAITV(8); ACONSUME(5, 2);
  WAITV(4); ACONSUME(6, 0);
  WAITV(0); ACONSUME(7, 1);
#undef TISSUE
#undef ACONSUME

  lds_barrier();   // S_rel visible

#pragma unroll
  for (int hh = 0; hh < 3; ++hh) {
    const int h = w * 3 + hh;
    const int sw = ((h >> 2) & 3) << 5;
    const size_t srow = (((size_t)b * 12 + h) * 512 + l) * 512;
    const unsigned short* sp = Sb + srow + lane;
    float sv[8];
    float mx = -1e30f;
#pragma unroll
    for (int j = 0; j < 8; ++j) {
      const int r = j * 64 + lane;
      float sr = bf2f(*(const unsigned short*)(X + h * 1024 + ((r * 2) ^ sw)));
      float s = (sr + bf2f(sp[j * 64])) * 0.125f;
      sv[j] = s;
      mx = fmaxf(mx, s);
    }
#pragma unroll
    for (int off = 32; off; off >>= 1) mx = fmaxf(mx, __shfl_xor(mx, off));
    float sm = 0.f;
#pragma unroll
    for (int j = 0; j < 8; ++j) { sv[j] = __expf(sv[j] - mx); sm += sv[j]; }
#pragma unroll
    for (int off = 32; off; off >>= 1) sm += __shfl_xor(sm, off);
    const float inv = 1.f / sm;
#pragma unroll
    for (int j = 0; j < 8; ++j)
      pbf[srow + j * 64 + lane] = f2bf(sv[j] * inv);
  }
}

// ---------------- K2c: rel-V context, contiguous streaming ----------------
__global__ __launch_bounds__(256, 2) void k_relv(
    const unsigned short* __restrict__ pbf,   // [B][H][L][R] bf16
    const float* __restrict__ relv,           // [B][R][L][D] f32
    unsigned short* __restrict__ part) {      // [4 rc][B][L][768] bf16
  __shared__ __align__(16) char PS[49152];    // P [12][16][128] bf16 swizzled
  const int tid = threadIdx.x, lane = tid & 63, w = tid >> 6;
  const int lg = blockIdx.x, rc = blockIdx.y, b = blockIdx.z;
  const int l0 = lg * 16, r0 = rc * 128;

  {
    const int x = tid & 15, rowb = tid >> 4;
#pragma unroll
    for (int pass = 0; pass < 12; ++pass) {
      const int ri = pass * 16 + rowb;
      const int h = ri >> 4, lr = ri & 15;
      const char* src = (const char*)pbf +
          ((((size_t)b * 12 + h) * 512 + l0 + lr) * 512 + r0) * 2 + (size_t)x * 16;
      u32x4 v = *(const u32x4*)src;
      *(u32x4*)(PS + h * 4096 + lr * 256 + ((x * 16) ^ ((lr & 3) << 4))) = v;
    }
  }
  __syncthreads();

  const int lr_w = w * 4 + (lane >> 4);
  const int l = l0 + lr_w;
  const char* rvb = (const char*)relv +
      (((size_t)b * 512 + r0) * 512 + l) * 256 + (size_t)(lane & 15) * 16;

  f32x4 vA[8], vB[8], vC[8];
  f32x4 acc[12];
#pragma unroll
  for (int h = 0; h < 12; ++h) acc[h] = {0.f, 0.f, 0.f, 0.f};

#define VISSUE(o, buf)                                                        \
  do {                                                                        \
    GL16(buf[0], rvb + (size_t)((o) * 8 + 0) * 131072, 0);                    \
    GL16(buf[1], rvb + (size_t)((o) * 8 + 1) * 131072, 0);                    \
    GL16(buf[2], rvb + (size_t)((o) * 8 + 2) * 131072, 0);                    \
    GL16(buf[3], rvb + (size_t)((o) * 8 + 3) * 131072, 0);                    \
    GL16(buf[4], rvb + (size_t)((o) * 8 + 4) * 131072, 0);                    \
    GL16(buf[5], rvb + (size_t)((o) * 8 + 5) * 131072, 0);                    \
    GL16(buf[6], rvb + (size_t)((o) * 8 + 6) * 131072, 0);                    \
    GL16(buf[7], rvb + (size_t)((o) * 8 + 7) * 131072, 0);                    \
  } while (0)
#define VCONS(o, buf)                                                         \
  do {                                                                        \
    _Pragma("unroll")                                                         \
    for (int h = 0; h < 12; ++h) {                                            \
      bf16x8 p8 = *(const bf16x8*)(PS + h * 4096 + lr_w * 256 +               \
                                   (((o) * 16) ^ ((lr_w & 3) << 4)));         \
      _Pragma("unroll")                                                       \
      for (int j = 0; j < 8; ++j) {                                           \
        const float pf = bf2f((unsigned short)p8[j]);                         \
        acc[h] += pf * buf[j];                                                \
      }                                                                       \
    }                                                                         \
  } while (0)

  VISSUE(0, vA);
  VISSUE(1, vB);
  VISSUE(2, vC);
  WAITV(16); VCONS(0, vA);  VISSUE(3, vA);
  WAITV(16); VCONS(1, vB);  VISSUE(4, vB);
  WAITV(16); VCONS(2, vC);  VISSUE(5, vC);
  WAITV(16); VCONS(3, vA);  VISSUE(6, vA);
  WAITV(16); VCONS(4, vB);  VISSUE(7, vB);
  WAITV(16); VCONS(5, vC);  VISSUE(8, vC);
  WAITV(16); VCONS(6, vA);  VISSUE(9, vA);
  WAITV(16); VCONS(7, vB);  VISSUE(10, vB);
  WAITV(16); VCONS(8, vC);  VISSUE(11, vC);
  WAITV(16); VCONS(9, vA);  VISSUE(12, vA);
  WAITV(16); VCONS(10, vB); VISSUE(13, vB);
  WAITV(16); VCONS(11, vC); VISSUE(14, vC);
  WAITV(16); VCONS(12, vA); VISSUE(15, vA);
  WAITV(16); VCONS(13, vB);
  WAITV(8);  VCONS(14, vC);
  WAITV(0);  VCONS(15, vA);
#undef VISSUE
#undef VCONS

  unsigned short* op = part + ((size_t)rc * 2048 + (size_t)b * 512 + l) * 768 + (lane & 15) * 4;
#pragma unroll
  for (int h = 0; h < 12; ++h) {
    u32x2 pk;
    pk.x = cvtpk(acc[h][0], acc[h][1]);
    pk.y = cvtpk(acc[h][2], acc[h][3]);
    *(u32x2*)(op + h * 64) = pk;
  }
}

// ---------------- K3: ctx = P@V per (b,h) via MFMA, + 4 bf16 partials -----
__global__ __launch_bounds__(256) void k_pv(
    const unsigned short* __restrict__ pbf, const unsigned short* __restrict__ vbt,
    const unsigned short* __restrict__ part, float* __restrict__ out) {
  __shared__ __align__(16) unsigned short lP[64 * 64];
  __shared__ __align__(16) unsigned short lV[64 * 64];
  const int tid = threadIdx.x, lane = tid & 63, w = tid >> 6;
  const int lt = blockIdx.x, bh = blockIdx.y;
  const int b = bh / 12, h = bh % 12;
  const int wm = (w >> 1) * 32, wn = (w & 1) * 32;
  f32x4 acc[2][2] = {};
  const char* pbase = (const char*)pbf + ((size_t)bh * 512 + lt * 64) * 1024;
  const char* vbase = (const char*)vbt + (size_t)bh * 64 * 1024;
  for (int kt = 0; kt < 8; ++kt) {
    __syncthreads();
#pragma unroll
    for (int i = 0; i < 2; ++i) {
      int e16 = i * 256 + tid;
      int row = e16 >> 3;
      int kb = (e16 & 7) * 16;
      int dst = row * 128 + (kb ^ ((row & 7) << 4));
      u32x4 vp = *(const u32x4*)(pbase + (size_t)row * 1024 + kt * 128 + kb);
      *(u32x4*)((char*)lP + dst) = vp;
      u32x4 vv = *(const u32x4*)(vbase + (size_t)row * 1024 + kt * 128 + kb);
      *(u32x4*)((char*)lV + dst) = vv;
    }
    __syncthreads();
#pragma unroll
    for (int ks = 0; ks < 2; ++ks) {
      bf16x8 fa[2], fb[2];
      const int kbyte = (ks * 32 + (lane >> 4) * 8) * 2;
#pragma unroll
      for (int mi = 0; mi < 2; ++mi) {
        int row = wm + mi * 16 + (lane & 15);
        fa[mi] = *(const bf16x8*)((const char*)lP + row * 128 + (kbyte ^ ((row & 7) << 4)));
      }
#pragma unroll
      for (int ni = 0; ni < 2; ++ni) {
        int row = wn + ni * 16 + (lane & 15);
        fb[ni] = *(const bf16x8*)((const char*)lV + row * 128 + (kbyte ^ ((row & 7) << 4)));
      }
#pragma unroll
      for (int mi = 0; mi < 2; ++mi)
#pragma unroll
        for (int ni = 0; ni < 2; ++ni)
          acc[mi][ni] = __builtin_amdgcn_mfma_f32_16x16x32_bf16(fa[mi], fb[ni], acc[mi][ni], 0, 0, 0);
    }
  }
#pragma unroll
  for (int mi = 0; mi < 2; ++mi)
#pragma unroll
    for (int ni = 0; ni < 2; ++ni) {
      int gd = wn + ni * 16 + (lane & 15);
#pragma unroll
      for (int r = 0; r < 4; ++r) {
        int gl = lt * 64 + wm + mi * 16 + ((lane >> 4) << 2) + r;
        size_t o = ((size_t)b * 512 + gl) * 768 + h * 64 + gd;
        out[o] = acc[mi][ni][r] + bf2f(part[o]) + bf2f(part[o + 1572864]) +
                 bf2f(part[o + 3145728]) + bf2f(part[o + 4718592]);
      }
    }
}

extern "C" void kernel_launch(void* const* d_in, const int* in_sizes, int n_in,
                              void* d_out, int out_size, void* d_ws, size_t ws_size,
                              hipStream_t stream) {
  (void)in_sizes; (void)n_in; (void)out_size; (void)ws_size;
  const float* hidden = (const float*)d_in[0];
  const float* relk   = (const float*)d_in[1];
  const float* relv   = (const float*)d_in[2];
  const float* Wq     = (const float*)d_in[3];
  const float* bq     = (const float*)d_in[4];
  const float* Wk     = (const float*)d_in[5];
  const float* bk     = (const float*)d_in[6];
  const float* Wv     = (const float*)d_in[7];
  const float* bv     = (const float*)d_in[8];
  float* out = (float*)d_out;
  char* ws = (char*)d_ws;

  unsigned short* hb  = (unsigned short*)(ws);
  unsigned short* wt  = (unsigned short*)(ws + 3145728);
  unsigned short* qbf = (unsigned short*)(ws + 6684672);
  unsigned short* kbf = (unsigned short*)(ws + 9830400);
  unsigned short* vbt = (unsigned short*)(ws + 12976128);
  unsigned short* Sb  = (unsigned short*)(ws + 16121856);  // dead after k_relA
  unsigned short* part= (unsigned short*)(ws + 16121856);  // 12.6 MB overlay
  unsigned short* pbf = (unsigned short*)(ws + 66453504);

  k_prep<<<1968, 256, 0, stream>>>(hidden, Wq, Wk, Wv, hb, wt);
  k_qkv_gemm<<<dim3(16, 18), 256, 0, stream>>>(hb, wt, bq, bk, bv, qbf, kbf, vbt);
  k_scores<<<dim3(8, 8, 48), 256, 0, stream>>>(qbf, kbf, Sb);
  k_relA<<<2048, 256, 0, stream>>>(qbf, relk, Sb, pbf);
  k_relv<<<dim3(32, 4, 4), 256, 0, stream>>>(pbf, relv, part);
  k_pv<<<dim3(8, 48), 256, 0, stream>>>(pbf, vbt, part, out);
}

// Round 12
// 186.804 us; speedup vs baseline: 1.0830x; 1.0830x over previous
//
#include <hip/hip_runtime.h>
#include <stdint.h>

// BertSelfAttentionWithRelation  B=4 L=512 H=12 D=64 HIDDEN=768
// Round 12: R10 base (best 181.0) + (1) XCD-chunked swizzle on qkv blocks
// (B-panel L2 locality), (2) k_relv 2-slot pipeline + bounds(256,3)
// (occupancy 2->3 blocks/CU; depth shown non-binding in R8/R9).

typedef __attribute__((ext_vector_type(8))) short bf16x8;
typedef __attribute__((ext_vector_type(4))) float f32x4;
typedef __attribute__((ext_vector_type(4))) unsigned int u32x4;
typedef __attribute__((ext_vector_type(2))) unsigned int u32x2;

__device__ __forceinline__ unsigned short f2bf(float f) {
  union { float f; unsigned int u; } v; v.f = f;
  unsigned int r = v.u + 0x7fffu + ((v.u >> 16) & 1u);
  return (unsigned short)(r >> 16);
}
__device__ __forceinline__ float bf2f(unsigned short s) {
  union { unsigned int u; float f; } v; v.u = ((unsigned int)s) << 16;
  return v.f;
}
__device__ __forceinline__ void lds_barrier() {
  asm volatile("s_waitcnt lgkmcnt(0)\ns_barrier" ::: "memory");
}
__device__ __forceinline__ unsigned cvtpk(float lo, float hi) {
  unsigned r;
  asm("v_cvt_pk_bf16_f32 %0, %1, %2" : "=v"(r) : "v"(lo), "v"(hi));
  return r;
}

#define GL16(dst, addr, OFF)                                                  \
  asm volatile("global_load_dwordx4 %0, %1, off offset:" #OFF                \
               : "=v"(dst) : "v"(addr))
#define WAITV(N)                                                              \
  do {                                                                        \
    asm volatile("s_waitcnt vmcnt(" #N ")" ::: "memory");                     \
    __builtin_amdgcn_sched_barrier(0);                                        \
  } while (0)

// ---------------- K0: merged hidden cvt + W transpose ----------------
__global__ void k_prep(const float* __restrict__ hidden,
                       const float* __restrict__ Wq, const float* __restrict__ Wk,
                       const float* __restrict__ Wv,
                       unsigned short* __restrict__ hb,
                       unsigned short* __restrict__ wt) {
  __shared__ float t[64][65];
  const int bid = blockIdx.x;
  if (bid >= 432) {
    int i = (bid - 432) * 256 + threadIdx.x;
    float4 v = reinterpret_cast<const float4*>(hidden)[i];
    ushort4 o;
    o.x = f2bf(v.x); o.y = f2bf(v.y); o.z = f2bf(v.z); o.w = f2bf(v.w);
    reinterpret_cast<ushort4*>(hb)[i] = o;
    return;
  }
  const int wsel = bid / 144, rem = bid % 144;
  const int kt = rem / 12, nt = rem % 12;
  const float* W = wsel == 0 ? Wq : (wsel == 1 ? Wk : Wv);
  const int lx = threadIdx.x & 63, ly = threadIdx.x >> 6;
  for (int i = 0; i < 64; i += 4)
    t[ly + i][lx] = W[(size_t)(kt * 64 + ly + i) * 768 + nt * 64 + lx];
  __syncthreads();
  for (int i = 0; i < 64; i += 4) {
    int r = ly + i;
    wt[((size_t)wsel * 768 + nt * 64 + r) * 768 + kt * 64 + lx] = f2bf(t[lx][r]);
  }
}

// ---------------- K1: fused QKV GEMM (bf16 MFMA, 64^2, XCD swizzle) -------
__global__ __launch_bounds__(256) void k_qkv_gemm(
    const unsigned short* __restrict__ A, const unsigned short* __restrict__ Bt,
    const float* __restrict__ bq, const float* __restrict__ bk, const float* __restrict__ bv,
    unsigned short* __restrict__ qbf, unsigned short* __restrict__ kbf,
    unsigned short* __restrict__ vbt) {
  __shared__ __align__(16) unsigned short lA[64 * 64];
  __shared__ __align__(16) unsigned short lB[64 * 64];
  const int tid = threadIdx.x, lane = tid & 63, w = tid >> 6;
  // XCD-chunked swizzle: 1152 blocks, 8 XCDs, 144/XCD (bijective, 1152%8==0).
  // Contiguous swz range per XCD -> consecutive n-panels stay in one L2.
  const int bid = blockIdx.y * 32 + blockIdx.x;
  const int swz = (bid & 7) * 144 + (bid >> 3);
  const int m0 = (swz & 31) * 64, n0 = (swz >> 5) * 64;
  const int wm = (w >> 1) * 32, wn = (w & 1) * 32;
  f32x4 acc[2][2] = {};

  for (int kt = 0; kt < 12; ++kt) {
    __syncthreads();
#pragma unroll
    for (int i = 0; i < 2; ++i) {
      int e16 = i * 256 + tid;
      int row = e16 >> 3;
      int kb = (e16 & 7) * 16;
      int dst = row * 128 + (kb ^ ((row & 7) << 4));
      u32x4 va = *(const u32x4*)((const char*)A + (size_t)(m0 + row) * 1536 + kt * 128 + kb);
      *(u32x4*)((char*)lA + dst) = va;
      u32x4 vb = *(const u32x4*)((const char*)Bt + (size_t)(n0 + row) * 1536 + kt * 128 + kb);
      *(u32x4*)((char*)lB + dst) = vb;
    }
    __syncthreads();
#pragma unroll
    for (int ks = 0; ks < 2; ++ks) {
      bf16x8 fa[2], fb[2];
      const int kbyte = (ks * 32 + (lane >> 4) * 8) * 2;
#pragma unroll
      for (int mi = 0; mi < 2; ++mi) {
        int row = wm + mi * 16 + (lane & 15);
        fa[mi] = *(const bf16x8*)((const char*)lA + row * 128 + (kbyte ^ ((row & 7) << 4)));
      }
#pragma unroll
      for (int ni = 0; ni < 2; ++ni) {
        int row = wn + ni * 16 + (lane & 15);
        fb[ni] = *(const bf16x8*)((const char*)lB + row * 128 + (kbyte ^ ((row & 7) << 4)));
      }
#pragma unroll
      for (int mi = 0; mi < 2; ++mi)
#pragma unroll
        for (int ni = 0; ni < 2; ++ni)
          acc[mi][ni] = __builtin_amdgcn_mfma_f32_16x16x32_bf16(fa[mi], fb[ni], acc[mi][ni], 0, 0, 0);
    }
  }
#pragma unroll
  for (int mi = 0; mi < 2; ++mi)
#pragma unroll
    for (int ni = 0; ni < 2; ++ni) {
      int gn = n0 + wn + ni * 16 + (lane & 15);
      float bias = (gn < 768) ? bq[gn] : (gn < 1536 ? bk[gn - 768] : bv[gn - 1536]);
#pragma unroll
      for (int r = 0; r < 4; ++r) {
        int gm = m0 + wm + mi * 16 + ((lane >> 4) << 2) + r;
        float val = acc[mi][ni][r] + bias;
        int b = gm >> 9, l = gm & 511;
        int d = gn & 63;
        if (gn < 768) {
          int h = gn >> 6;
          qbf[(((size_t)(b * 12 + h)) * 512 + l) * 64 + d] = f2bf(val);
        } else if (gn < 1536) {
          int h = (gn - 768) >> 6;
          kbf[(((size_t)(b * 12 + h)) * 512 + l) * 64 + d] = f2bf(val);
        } else {
          int h = (gn - 1536) >> 6;
          vbt[(((size_t)(b * 12 + h)) * 64 + d) * 512 + l] = f2bf(val);
        }
      }
    }
}

// ---------------- K2a: content scores S = q.k^T per (b,h), bf16 out -------
__global__ __launch_bounds__(256) void k_scores(
    const unsigned short* __restrict__ qbf, const unsigned short* __restrict__ kbf,
    unsigned short* __restrict__ Sb) {
  __shared__ __align__(16) unsigned short lQ[64 * 64];
  __shared__ __align__(16) unsigned short lK[64 * 64];
  const int tid = threadIdx.x, lane = tid & 63, w = tid >> 6;
  const int mt = blockIdx.x, lt = blockIdx.y, bh = blockIdx.z;
  const int wm = (w >> 1) * 32, wn = (w & 1) * 32;
  f32x4 acc[2][2] = {};
#pragma unroll
  for (int i = 0; i < 2; ++i) {
    int e16 = i * 256 + tid;
    int row = e16 >> 3;
    int kb = (e16 & 7) * 16;
    int dst = row * 128 + (kb ^ ((row & 7) << 4));
    u32x4 vq = *(const u32x4*)((const char*)qbf + ((size_t)bh * 512 + lt * 64 + row) * 128 + kb);
    *(u32x4*)((char*)lQ + dst) = vq;
    u32x4 vk = *(const u32x4*)((const char*)kbf + ((size_t)bh * 512 + mt * 64 + row) * 128 + kb);
    *(u32x4*)((char*)lK + dst) = vk;
  }
  __syncthreads();
#pragma unroll
  for (int ks = 0; ks < 2; ++ks) {
    bf16x8 fa[2], fb[2];
    const int kbyte = (ks * 32 + (lane >> 4) * 8) * 2;
#pragma unroll
    for (int mi = 0; mi < 2; ++mi) {
      int row = wm + mi * 16 + (lane & 15);
      fa[mi] = *(const bf16x8*)((const char*)lQ + row * 128 + (kbyte ^ ((row & 7) << 4)));
    }
#pragma unroll
    for (int ni = 0; ni < 2; ++ni) {
      int row = wn + ni * 16 + (lane & 15);
      fb[ni] = *(const bf16x8*)((const char*)lK + row * 128 + (kbyte ^ ((row & 7) << 4)));
    }
#pragma unroll
    for (int mi = 0; mi < 2; ++mi)
#pragma unroll
      for (int ni = 0; ni < 2; ++ni)
        acc[mi][ni] = __builtin_amdgcn_mfma_f32_16x16x32_bf16(fa[mi], fb[ni], acc[mi][ni], 0, 0, 0);
  }
#pragma unroll
  for (int mi = 0; mi < 2; ++mi)
#pragma unroll
    for (int ni = 0; ni < 2; ++ni) {
      int gm = mt * 64 + wn + ni * 16 + (lane & 15);
#pragma unroll
      for (int r = 0; r < 4; ++r) {
        int gl = lt * 64 + wm + mi * 16 + ((lane >> 4) << 2) + r;
        Sb[(size_t)bh * 262144 + (size_t)gl * 512 + gm] = f2bf(acc[mi][ni][r]);
      }
    }
}

// ---------------- K2b: rel-K scores + softmax -> pbf, one block per (b,l) --
__global__ __launch_bounds__(256, 5) void k_relA(
    const unsigned short* __restrict__ qbf,
    const float* __restrict__ relk,   // [B][L][L][D]  (b, l, r, d)
    const unsigned short* __restrict__ Sb,
    unsigned short* __restrict__ pbf) {
  __shared__ __align__(16) char X[12288];
  const int tid = threadIdx.x, lane = tid & 63, w = tid >> 6;
  const int bl = blockIdx.x, b = bl >> 9, l = bl & 511;
  const int lm = lane & 15, lg = lane >> 4;
  const int hq = lm < 12 ? lm : 11;

  union { f32x4 f; bf16x8 b; } qa0, qa1;
  const char* aQ = (const char*)qbf + (((size_t)b * 12 + hq) * 512 + l) * 128 + (size_t)lg * 16;
  GL16(qa0.f, aQ, 0);
  GL16(qa1.f, aQ, 64);

  const char* aA = (const char*)relk + (size_t)bl * 131072 +
                   (size_t)(w * 128 + lm) * 256 + (size_t)lg * 32;
  f32x4 td[3][4];
#define TISSUE(t, s)                                                          \
  do {                                                                        \
    const char* p_ = aA + (size_t)(t) * 4096;                                 \
    GL16(td[s][0], p_, 0);   GL16(td[s][1], p_, 16);                          \
    GL16(td[s][2], p_, 128); GL16(td[s][3], p_, 144);                         \
  } while (0)
#define ACONSUME(t, s)                                                        \
  do {                                                                        \
    union { bf16x8 v; unsigned u[4]; } fb0, fb1;                              \
    fb0.u[0] = cvtpk(td[s][0][0], td[s][0][1]);                               \
    fb0.u[1] = cvtpk(td[s][0][2], td[s][0][3]);                               \
    fb0.u[2] = cvtpk(td[s][1][0], td[s][1][1]);                               \
    fb0.u[3] = cvtpk(td[s][1][2], td[s][1][3]);                               \
    fb1.u[0] = cvtpk(td[s][2][0], td[s][2][1]);                               \
    fb1.u[1] = cvtpk(td[s][2][2], td[s][2][3]);                               \
    fb1.u[2] = cvtpk(td[s][3][0], td[s][3][1]);                               \
    fb1.u[3] = cvtpk(td[s][3][2], td[s][3][3]);                               \
    f32x4 acc = {0.f, 0.f, 0.f, 0.f};                                         \
    acc = __builtin_amdgcn_mfma_f32_16x16x32_bf16(qa0.b, fb0.v, acc, 0, 0, 0);\
    acc = __builtin_amdgcn_mfma_f32_16x16x32_bf16(qa1.b, fb1.v, acc, 0, 0, 0);\
    if (lg < 3) {                                                             \
      const int r_ = w * 128 + (t) * 16 + lm;                                 \
      _Pragma("unroll")                                                       \
      for (int reg = 0; reg < 4; ++reg) {                                     \
        const int h_ = lg * 4 + reg;                                          \
        *(unsigned short*)(X + h_ * 1024 +                                    \
                           ((r_ * 2) ^ (((h_ >> 2) & 3) << 5))) =             \
            f2bf(acc[reg]);                                                   \
      }                                                                       \
    }                                                                         \
  } while (0)

  TISSUE(0, 0); TISSUE(1, 1); TISSUE(2, 2);
  WAITV(8); ACONSUME(0, 0); TISSUE(3, 0);
  WAITV(8); ACONSUME(1, 1); TISSUE(4, 1);
  WAITV(8); ACONSUME(2, 2); TISSUE(5, 2);
  WAITV(8); ACONSUME(3, 0); TISSUE(6, 0);
  WAITV(8); ACONSUME(4, 1); TISSUE(7, 1);
  WAITV(8); ACONSUME(5, 2);
  WAITV(4); ACONSUME(6, 0);
  WAITV(0); ACONSUME(7, 1);
#undef TISSUE
#undef ACONSUME

  lds_barrier();   // S_rel visible

#pragma unroll
  for (int hh = 0; hh < 3; ++hh) {
    const int h = w * 3 + hh;
    const int sw = ((h >> 2) & 3) << 5;
    const size_t srow = (((size_t)b * 12 + h) * 512 + l) * 512;
    const unsigned short* sp = Sb + srow + lane;
    float sv[8];
    float mx = -1e30f;
#pragma unroll
    for (int j = 0; j < 8; ++j) {
      const int r = j * 64 + lane;
      float sr = bf2f(*(const unsigned short*)(X + h * 1024 + ((r * 2) ^ sw)));
      float s = (sr + bf2f(sp[j * 64])) * 0.125f;
      sv[j] = s;
      mx = fmaxf(mx, s);
    }
#pragma unroll
    for (int off = 32; off; off >>= 1) mx = fmaxf(mx, __shfl_xor(mx, off));
    float sm = 0.f;
#pragma unroll
    for (int j = 0; j < 8; ++j) { sv[j] = __expf(sv[j] - mx); sm += sv[j]; }
#pragma unroll
    for (int off = 32; off; off >>= 1) sm += __shfl_xor(sm, off);
    const float inv = 1.f / sm;
#pragma unroll
    for (int j = 0; j < 8; ++j)
      pbf[srow + j * 64 + lane] = f2bf(sv[j] * inv);
  }
}

// ---------------- K2c: rel-V context, 2-slot pipeline, 3 blocks/CU --------
__global__ __launch_bounds__(256, 3) void k_relv(
    const unsigned short* __restrict__ pbf,   // [B][H][L][R] bf16
    const float* __restrict__ relv,           // [B][R][L][D] f32
    unsigned short* __restrict__ part) {      // [4 rc][B][L][768] bf16
  __shared__ __align__(16) char PS[49152];    // P [12][16][128] bf16 swizzled
  const int tid = threadIdx.x, lane = tid & 63, w = tid >> 6;
  const int lg = blockIdx.x, rc = blockIdx.y, b = blockIdx.z;
  const int l0 = lg * 16, r0 = rc * 128;

  {
    const int x = tid & 15, rowb = tid >> 4;
#pragma unroll
    for (int pass = 0; pass < 12; ++pass) {
      const int ri = pass * 16 + rowb;
      const int h = ri >> 4, lr = ri & 15;
      const char* src = (const char*)pbf +
          ((((size_t)b * 12 + h) * 512 + l0 + lr) * 512 + r0) * 2 + (size_t)x * 16;
      u32x4 v = *(const u32x4*)src;
      *(u32x4*)(PS + h * 4096 + lr * 256 + ((x * 16) ^ ((lr & 3) << 4))) = v;
    }
  }
  __syncthreads();

  const int lr_w = w * 4 + (lane >> 4);
  const int l = l0 + lr_w;
  const char* rvb = (const char*)relv +
      (((size_t)b * 512 + r0) * 512 + l) * 256 + (size_t)(lane & 15) * 16;

  f32x4 vA[8], vB[8];
  f32x4 acc[12];
#pragma unroll
  for (int h = 0; h < 12; ++h) acc[h] = {0.f, 0.f, 0.f, 0.f};

#define VISSUE(o, buf)                                                        \
  do {                                                                        \
    GL16(buf[0], rvb + (size_t)((o) * 8 + 0) * 131072, 0);                    \
    GL16(buf[1], rvb + (size_t)((o) * 8 + 1) * 131072, 0);                    \
    GL16(buf[2], rvb + (size_t)((o) * 8 + 2) * 131072, 0);                    \
    GL16(buf[3], rvb + (size_t)((o) * 8 + 3) * 131072, 0);                    \
    GL16(buf[4], rvb + (size_t)((o) * 8 + 4) * 131072, 0);                    \
    GL16(buf[5], rvb + (size_t)((o) * 8 + 5) * 131072, 0);                    \
    GL16(buf[6], rvb + (size_t)((o) * 8 + 6) * 131072, 0);                    \
    GL16(buf[7], rvb + (size_t)((o) * 8 + 7) * 131072, 0);                    \
  } while (0)
#define VCONS(o, buf)                                                         \
  do {                                                                        \
    _Pragma("unroll")                                                         \
    for (int h = 0; h < 12; ++h) {                                            \
      bf16x8 p8 = *(const bf16x8*)(PS + h * 4096 + lr_w * 256 +               \
                                   (((o) * 16) ^ ((lr_w & 3) << 4)));         \
      _Pragma("unroll")                                                       \
      for (int j = 0; j < 8; ++j) {                                           \
        const float pf = bf2f((unsigned short)p8[j]);                         \
        acc[h] += pf * buf[j];                                                \
      }                                                                       \
    }                                                                         \
  } while (0)

  VISSUE(0, vA);
  VISSUE(1, vB);
  WAITV(8); VCONS(0, vA);  VISSUE(2, vA);
  WAITV(8); VCONS(1, vB);  VISSUE(3, vB);
  WAITV(8); VCONS(2, vA);  VISSUE(4, vA);
  WAITV(8); VCONS(3, vB);  VISSUE(5, vB);
  WAITV(8); VCONS(4, vA);  VISSUE(6, vA);
  WAITV(8); VCONS(5, vB);  VISSUE(7, vB);
  WAITV(8); VCONS(6, vA);  VISSUE(8, vA);
  WAITV(8); VCONS(7, vB);  VISSUE(9, vB);
  WAITV(8); VCONS(8, vA);  VISSUE(10, vA);
  WAITV(8); VCONS(9, vB);  VISSUE(11, vB);
  WAITV(8); VCONS(10, vA); VISSUE(12, vA);
  WAITV(8); VCONS(11, vB); VISSUE(13, vB);
  WAITV(8); VCONS(12, vA); VISSUE(14, vA);
  WAITV(8); VCONS(13, vB); VISSUE(15, vB);
  WAITV(8); VCONS(14, vA);
  WAITV(0); VCONS(15, vB);
#undef VISSUE
#undef VCONS

  unsigned short* op = part + ((size_t)rc * 2048 + (size_t)b * 512 + l) * 768 + (lane & 15) * 4;
#pragma unroll
  for (int h = 0; h < 12; ++h) {
    u32x2 pk;
    pk.x = cvtpk(acc[h][0], acc[h][1]);
    pk.y = cvtpk(acc[h][2], acc[h][3]);
    *(u32x2*)(op + h * 64) = pk;
  }
}

// ---------------- K3: ctx = P@V per (b,h) via MFMA, + 4 bf16 partials -----
__global__ __launch_bounds__(256) void k_pv(
    const unsigned short* __restrict__ pbf, const unsigned short* __restrict__ vbt,
    const unsigned short* __restrict__ part, float* __restrict__ out) {
  __shared__ __align__(16) unsigned short lP[64 * 64];
  __shared__ __align__(16) unsigned short lV[64 * 64];
  const int tid = threadIdx.x, lane = tid & 63, w = tid >> 6;
  const int lt = blockIdx.x, bh = blockIdx.y;
  const int b = bh / 12, h = bh % 12;
  const int wm = (w >> 1) * 32, wn = (w & 1) * 32;
  f32x4 acc[2][2] = {};
  const char* pbase = (const char*)pbf + ((size_t)bh * 512 + lt * 64) * 1024;
  const char* vbase = (const char*)vbt + (size_t)bh * 64 * 1024;
  for (int kt = 0; kt < 8; ++kt) {
    __syncthreads();
#pragma unroll
    for (int i = 0; i < 2; ++i) {
      int e16 = i * 256 + tid;
      int row = e16 >> 3;
      int kb = (e16 & 7) * 16;
      int dst = row * 128 + (kb ^ ((row & 7) << 4));
      u32x4 vp = *(const u32x4*)(pbase + (size_t)row * 1024 + kt * 128 + kb);
      *(u32x4*)((char*)lP + dst) = vp;
      u32x4 vv = *(const u32x4*)(vbase + (size_t)row * 1024 + kt * 128 + kb);
      *(u32x4*)((char*)lV + dst) = vv;
    }
    __syncthreads();
#pragma unroll
    for (int ks = 0; ks < 2; ++ks) {
      bf16x8 fa[2], fb[2];
      const int kbyte = (ks * 32 + (lane >> 4) * 8) * 2;
#pragma unroll
      for (int mi = 0; mi < 2; ++mi) {
        int row = wm + mi * 16 + (lane & 15);
        fa[mi] = *(const bf16x8*)((const char*)lP + row * 128 + (kbyte ^ ((row & 7) << 4)));
      }
#pragma unroll
      for (int ni = 0; ni < 2; ++ni) {
        int row = wn + ni * 16 + (lane & 15);
        fb[ni] = *(const bf16x8*)((const char*)lV + row * 128 + (kbyte ^ ((row & 7) << 4)));
      }
#pragma unroll
      for (int mi = 0; mi < 2; ++mi)
#pragma unroll
        for (int ni = 0; ni < 2; ++ni)
          acc[mi][ni] = __builtin_amdgcn_mfma_f32_16x16x32_bf16(fa[mi], fb[ni], acc[mi][ni], 0, 0, 0);
    }
  }
#pragma unroll
  for (int mi = 0; mi < 2; ++mi)
#pragma unroll
    for (int ni = 0; ni < 2; ++ni) {
      int gd = wn + ni * 16 + (lane & 15);
#pragma unroll
      for (int r = 0; r < 4; ++r) {
        int gl = lt * 64 + wm + mi * 16 + ((lane >> 4) << 2) + r;
        size_t o = ((size_t)b * 512 + gl) * 768 + h * 64 + gd;
        out[o] = acc[mi][ni][r] + bf2f(part[o]) + bf2f(part[o + 1572864]) +
                 bf2f(part[o + 3145728]) + bf2f(part[o + 4718592]);
      }
    }
}

extern "C" void kernel_launch(void* const* d_in, const int* in_sizes, int n_in,
                              void* d_out, int out_size, void* d_ws, size_t ws_size,
                              hipStream_t stream) {
  (void)in_sizes; (void)n_in; (void)out_size; (void)ws_size;
  const float* hidden = (const float*)d_in[0];
  const float* relk   = (const float*)d_in[1];
  const float* relv   = (const float*)d_in[2];
  const float* Wq     = (const float*)d_in[3];
  const float* bq     = (const float*)d_in[4];
  const float* Wk     = (const float*)d_in[5];
  const float* bk     = (const float*)d_in[6];
  const float* Wv     = (const float*)d_in[7];
  const float* bv     = (const float*)d_in[8];
  float* out = (float*)d_out;
  char* ws = (char*)d_ws;

  unsigned short* hb  = (unsigned short*)(ws);
  unsigned short* wt  = (unsigned short*)(ws + 3145728);
  unsigned short* qbf = (unsigned short*)(ws + 6684672);
  unsigned short* kbf = (unsigned short*)(ws + 9830400);
  unsigned short* vbt = (unsigned short*)(ws + 12976128);
  unsigned short* Sb  = (unsigned short*)(ws + 16121856);  // dead after k_relA
  unsigned short* part= (unsigned short*)(ws + 16121856);  // 12.6 MB overlay
  unsigned short* pbf = (unsigned short*)(ws + 66453504);

  k_prep<<<1968, 256, 0, stream>>>(hidden, Wq, Wk, Wv, hb, wt);
  k_qkv_gemm<<<dim3(32, 36), 256, 0, stream>>>(hb, wt, bq, bk, bv, qbf, kbf, vbt);
  k_scores<<<dim3(8, 8, 48), 256, 0, stream>>>(qbf, kbf, Sb);
  k_relA<<<2048, 256, 0, stream>>>(qbf, relk, Sb, pbf);
  k_relv<<<dim3(32, 4, 4), 256, 0, stream>>>(pbf, relv, part);
  k_pv<<<dim3(8, 48), 256, 0, stream>>>(pbf, vbt, part, out);
}

// Round 13
// 181.362 us; speedup vs baseline: 1.1155x; 1.0300x over previous
//
#include <hip/hip_runtime.h>
#include <stdint.h>

// BertSelfAttentionWithRelation  B=4 L=512 H=12 D=64 HIDDEN=768
// Round 13: exact revert to R10 (best measured: 181.0 us).
//   R11 (128^2 qkv tile): -21 us regression (288 blocks = 1/CU, exposed drains)
//   R12 (qkv XCD swizzle + relv bounds(256,3)): -5.8 us regression
//   Pipeline: k_prep (cvt+transpose) -> k_qkv_gemm (64^2 MFMA) ->
//     k_scores (bf16 S) -> k_relA (MFMA relk + softmax, 12KB LDS, 5 blk/CU)
//     -> k_relv (contiguous relv stream, 3-slot counted vmcnt) -> k_pv.

typedef __attribute__((ext_vector_type(8))) short bf16x8;
typedef __attribute__((ext_vector_type(4))) float f32x4;
typedef __attribute__((ext_vector_type(4))) unsigned int u32x4;
typedef __attribute__((ext_vector_type(2))) unsigned int u32x2;

__device__ __forceinline__ unsigned short f2bf(float f) {
  union { float f; unsigned int u; } v; v.f = f;
  unsigned int r = v.u + 0x7fffu + ((v.u >> 16) & 1u);
  return (unsigned short)(r >> 16);
}
__device__ __forceinline__ float bf2f(unsigned short s) {
  union { unsigned int u; float f; } v; v.u = ((unsigned int)s) << 16;
  return v.f;
}
__device__ __forceinline__ void lds_barrier() {
  asm volatile("s_waitcnt lgkmcnt(0)\ns_barrier" ::: "memory");
}
__device__ __forceinline__ unsigned cvtpk(float lo, float hi) {
  unsigned r;
  asm("v_cvt_pk_bf16_f32 %0, %1, %2" : "=v"(r) : "v"(lo), "v"(hi));
  return r;
}

#define GL16(dst, addr, OFF)                                                  \
  asm volatile("global_load_dwordx4 %0, %1, off offset:" #OFF                \
               : "=v"(dst) : "v"(addr))
#define WAITV(N)                                                              \
  do {                                                                        \
    asm volatile("s_waitcnt vmcnt(" #N ")" ::: "memory");                     \
    __builtin_amdgcn_sched_barrier(0);                                        \
  } while (0)

// ---------------- K0: merged hidden cvt + W transpose ----------------
__global__ void k_prep(const float* __restrict__ hidden,
                       const float* __restrict__ Wq, const float* __restrict__ Wk,
                       const float* __restrict__ Wv,
                       unsigned short* __restrict__ hb,
                       unsigned short* __restrict__ wt) {
  __shared__ float t[64][65];
  const int bid = blockIdx.x;
  if (bid >= 432) {
    int i = (bid - 432) * 256 + threadIdx.x;
    float4 v = reinterpret_cast<const float4*>(hidden)[i];
    ushort4 o;
    o.x = f2bf(v.x); o.y = f2bf(v.y); o.z = f2bf(v.z); o.w = f2bf(v.w);
    reinterpret_cast<ushort4*>(hb)[i] = o;
    return;
  }
  const int wsel = bid / 144, rem = bid % 144;
  const int kt = rem / 12, nt = rem % 12;
  const float* W = wsel == 0 ? Wq : (wsel == 1 ? Wk : Wv);
  const int lx = threadIdx.x & 63, ly = threadIdx.x >> 6;
  for (int i = 0; i < 64; i += 4)
    t[ly + i][lx] = W[(size_t)(kt * 64 + ly + i) * 768 + nt * 64 + lx];
  __syncthreads();
  for (int i = 0; i < 64; i += 4) {
    int r = ly + i;
    wt[((size_t)wsel * 768 + nt * 64 + r) * 768 + kt * 64 + lx] = f2bf(t[lx][r]);
  }
}

// ---------------- K1: fused QKV GEMM (bf16 MFMA, 64^2 tile) ----------------
__global__ __launch_bounds__(256) void k_qkv_gemm(
    const unsigned short* __restrict__ A, const unsigned short* __restrict__ Bt,
    const float* __restrict__ bq, const float* __restrict__ bk, const float* __restrict__ bv,
    unsigned short* __restrict__ qbf, unsigned short* __restrict__ kbf,
    unsigned short* __restrict__ vbt) {
  __shared__ __align__(16) unsigned short lA[64 * 64];
  __shared__ __align__(16) unsigned short lB[64 * 64];
  const int tid = threadIdx.x, lane = tid & 63, w = tid >> 6;
  const int m0 = blockIdx.x * 64, n0 = blockIdx.y * 64;
  const int wm = (w >> 1) * 32, wn = (w & 1) * 32;
  f32x4 acc[2][2] = {};

  for (int kt = 0; kt < 12; ++kt) {
    __syncthreads();
#pragma unroll
    for (int i = 0; i < 2; ++i) {
      int e16 = i * 256 + tid;
      int row = e16 >> 3;
      int kb = (e16 & 7) * 16;
      int dst = row * 128 + (kb ^ ((row & 7) << 4));
      u32x4 va = *(const u32x4*)((const char*)A + (size_t)(m0 + row) * 1536 + kt * 128 + kb);
      *(u32x4*)((char*)lA + dst) = va;
      u32x4 vb = *(const u32x4*)((const char*)Bt + (size_t)(n0 + row) * 1536 + kt * 128 + kb);
      *(u32x4*)((char*)lB + dst) = vb;
    }
    __syncthreads();
#pragma unroll
    for (int ks = 0; ks < 2; ++ks) {
      bf16x8 fa[2], fb[2];
      const int kbyte = (ks * 32 + (lane >> 4) * 8) * 2;
#pragma unroll
      for (int mi = 0; mi < 2; ++mi) {
        int row = wm + mi * 16 + (lane & 15);
        fa[mi] = *(const bf16x8*)((const char*)lA + row * 128 + (kbyte ^ ((row & 7) << 4)));
      }
#pragma unroll
      for (int ni = 0; ni < 2; ++ni) {
        int row = wn + ni * 16 + (lane & 15);
        fb[ni] = *(const bf16x8*)((const char*)lB + row * 128 + (kbyte ^ ((row & 7) << 4)));
      }
#pragma unroll
      for (int mi = 0; mi < 2; ++mi)
#pragma unroll
        for (int ni = 0; ni < 2; ++ni)
          acc[mi][ni] = __builtin_amdgcn_mfma_f32_16x16x32_bf16(fa[mi], fb[ni], acc[mi][ni], 0, 0, 0);
    }
  }
#pragma unroll
  for (int mi = 0; mi < 2; ++mi)
#pragma unroll
    for (int ni = 0; ni < 2; ++ni) {
      int gn = n0 + wn + ni * 16 + (lane & 15);
      float bias = (gn < 768) ? bq[gn] : (gn < 1536 ? bk[gn - 768] : bv[gn - 1536]);
#pragma unroll
      for (int r = 0; r < 4; ++r) {
        int gm = m0 + wm + mi * 16 + ((lane >> 4) << 2) + r;
        float val = acc[mi][ni][r] + bias;
        int b = gm >> 9, l = gm & 511;
        int d = gn & 63;
        if (gn < 768) {
          int h = gn >> 6;
          qbf[(((size_t)(b * 12 + h)) * 512 + l) * 64 + d] = f2bf(val);
        } else if (gn < 1536) {
          int h = (gn - 768) >> 6;
          kbf[(((size_t)(b * 12 + h)) * 512 + l) * 64 + d] = f2bf(val);
        } else {
          int h = (gn - 1536) >> 6;
          vbt[(((size_t)(b * 12 + h)) * 64 + d) * 512 + l] = f2bf(val);
        }
      }
    }
}

// ---------------- K2a: content scores S = q.k^T per (b,h), bf16 out -------
__global__ __launch_bounds__(256) void k_scores(
    const unsigned short* __restrict__ qbf, const unsigned short* __restrict__ kbf,
    unsigned short* __restrict__ Sb) {
  __shared__ __align__(16) unsigned short lQ[64 * 64];
  __shared__ __align__(16) unsigned short lK[64 * 64];
  const int tid = threadIdx.x, lane = tid & 63, w = tid >> 6;
  const int mt = blockIdx.x, lt = blockIdx.y, bh = blockIdx.z;
  const int wm = (w >> 1) * 32, wn = (w & 1) * 32;
  f32x4 acc[2][2] = {};
#pragma unroll
  for (int i = 0; i < 2; ++i) {
    int e16 = i * 256 + tid;
    int row = e16 >> 3;
    int kb = (e16 & 7) * 16;
    int dst = row * 128 + (kb ^ ((row & 7) << 4));
    u32x4 vq = *(const u32x4*)((const char*)qbf + ((size_t)bh * 512 + lt * 64 + row) * 128 + kb);
    *(u32x4*)((char*)lQ + dst) = vq;
    u32x4 vk = *(const u32x4*)((const char*)kbf + ((size_t)bh * 512 + mt * 64 + row) * 128 + kb);
    *(u32x4*)((char*)lK + dst) = vk;
  }
  __syncthreads();
#pragma unroll
  for (int ks = 0; ks < 2; ++ks) {
    bf16x8 fa[2], fb[2];
    const int kbyte = (ks * 32 + (lane >> 4) * 8) * 2;
#pragma unroll
    for (int mi = 0; mi < 2; ++mi) {
      int row = wm + mi * 16 + (lane & 15);
      fa[mi] = *(const bf16x8*)((const char*)lQ + row * 128 + (kbyte ^ ((row & 7) << 4)));
    }
#pragma unroll
    for (int ni = 0; ni < 2; ++ni) {
      int row = wn + ni * 16 + (lane & 15);
      fb[ni] = *(const bf16x8*)((const char*)lK + row * 128 + (kbyte ^ ((row & 7) << 4)));
    }
#pragma unroll
    for (int mi = 0; mi < 2; ++mi)
#pragma unroll
      for (int ni = 0; ni < 2; ++ni)
        acc[mi][ni] = __builtin_amdgcn_mfma_f32_16x16x32_bf16(fa[mi], fb[ni], acc[mi][ni], 0, 0, 0);
  }
#pragma unroll
  for (int mi = 0; mi < 2; ++mi)
#pragma unroll
    for (int ni = 0; ni < 2; ++ni) {
      int gm = mt * 64 + wn + ni * 16 + (lane & 15);
#pragma unroll
      for (int r = 0; r < 4; ++r) {
        int gl = lt * 64 + wm + mi * 16 + ((lane >> 4) << 2) + r;
        Sb[(size_t)bh * 262144 + (size_t)gl * 512 + gm] = f2bf(acc[mi][ni][r]);
      }
    }
}

// ---------------- K2b: rel-K scores + softmax -> pbf, one block per (b,l) --
__global__ __launch_bounds__(256, 5) void k_relA(
    const unsigned short* __restrict__ qbf,
    const float* __restrict__ relk,   // [B][L][L][D]  (b, l, r, d)
    const unsigned short* __restrict__ Sb,
    unsigned short* __restrict__ pbf) {
  __shared__ __align__(16) char X[12288];
  const int tid = threadIdx.x, lane = tid & 63, w = tid >> 6;
  const int bl = blockIdx.x, b = bl >> 9, l = bl & 511;
  const int lm = lane & 15, lg = lane >> 4;
  const int hq = lm < 12 ? lm : 11;

  union { f32x4 f; bf16x8 b; } qa0, qa1;
  const char* aQ = (const char*)qbf + (((size_t)b * 12 + hq) * 512 + l) * 128 + (size_t)lg * 16;
  GL16(qa0.f, aQ, 0);
  GL16(qa1.f, aQ, 64);

  const char* aA = (const char*)relk + (size_t)bl * 131072 +
                   (size_t)(w * 128 + lm) * 256 + (size_t)lg * 32;
  f32x4 td[3][4];
#define TISSUE(t, s)                                                          \
  do {                                                                        \
    const char* p_ = aA + (size_t)(t) * 4096;                                 \
    GL16(td[s][0], p_, 0);   GL16(td[s][1], p_, 16);                          \
    GL16(td[s][2], p_, 128); GL16(td[s][3], p_, 144);                         \
  } while (0)
#define ACONSUME(t, s)                                                        \
  do {                                                                        \
    union { bf16x8 v; unsigned u[4]; } fb0, fb1;                              \
    fb0.u[0] = cvtpk(td[s][0][0], td[s][0][1]);                               \
    fb0.u[1] = cvtpk(td[s][0][2], td[s][0][3]);                               \
    fb0.u[2] = cvtpk(td[s][1][0], td[s][1][1]);                               \
    fb0.u[3] = cvtpk(td[s][1][2], td[s][1][3]);                               \
    fb1.u[0] = cvtpk(td[s][2][0], td[s][2][1]);                               \
    fb1.u[1] = cvtpk(td[s][2][2], td[s][2][3]);                               \
    fb1.u[2] = cvtpk(td[s][3][0], td[s][3][1]);                               \
    fb1.u[3] = cvtpk(td[s][3][2], td[s][3][3]);                               \
    f32x4 acc = {0.f, 0.f, 0.f, 0.f};                                         \
    acc = __builtin_amdgcn_mfma_f32_16x16x32_bf16(qa0.b, fb0.v, acc, 0, 0, 0);\
    acc = __builtin_amdgcn_mfma_f32_16x16x32_bf16(qa1.b, fb1.v, acc, 0, 0, 0);\
    if (lg < 3) {                                                             \
      const int r_ = w * 128 + (t) * 16 + lm;                                 \
      _Pragma("unroll")                                                       \
      for (int reg = 0; reg < 4; ++reg) {                                     \
        const int h_ = lg * 4 + reg;                                          \
        *(unsigned short*)(X + h_ * 1024 +                                    \
                           ((r_ * 2) ^ (((h_ >> 2) & 3) << 5))) =             \
            f2bf(acc[reg]);                                                   \
      }                                                                       \
    }                                                                         \
  } while (0)

  TISSUE(0, 0); TISSUE(1, 1); TISSUE(2, 2);
  WAITV(8); ACONSUME(0, 0); TISSUE(3, 0);
  WAITV(8); ACONSUME(1, 1); TISSUE(4, 1);
  WAITV(8); ACONSUME(2, 2); TISSUE(5, 2);
  WAITV(8); ACONSUME(3, 0); TISSUE(6, 0);
  WAITV(8); ACONSUME(4, 1); TISSUE(7, 1);
  WAITV(8); ACONSUME(5, 2);
  WAITV(4); ACONSUME(6, 0);
  WAITV(0); ACONSUME(7, 1);
#undef TISSUE
#undef ACONSUME

  lds_barrier();   // S_rel visible

#pragma unroll
  for (int hh = 0; hh < 3; ++hh) {
    const int h = w * 3 + hh;
    const int sw = ((h >> 2) & 3) << 5;
    const size_t srow = (((size_t)b * 12 + h) * 512 + l) * 512;
    const unsigned short* sp = Sb + srow + lane;
    float sv[8];
    float mx = -1e30f;
#pragma unroll
    for (int j = 0; j < 8; ++j) {
      const int r = j * 64 + lane;
      float sr = bf2f(*(const unsigned short*)(X + h * 1024 + ((r * 2) ^ sw)));
      float s = (sr + bf2f(sp[j * 64])) * 0.125f;
      sv[j] = s;
      mx = fmaxf(mx, s);
    }
#pragma unroll
    for (int off = 32; off; off >>= 1) mx = fmaxf(mx, __shfl_xor(mx, off));
    float sm = 0.f;
#pragma unroll
    for (int j = 0; j < 8; ++j) { sv[j] = __expf(sv[j] - mx); sm += sv[j]; }
#pragma unroll
    for (int off = 32; off; off >>= 1) sm += __shfl_xor(sm, off);
    const float inv = 1.f / sm;
#pragma unroll
    for (int j = 0; j < 8; ++j)
      pbf[srow + j * 64 + lane] = f2bf(sv[j] * inv);
  }
}

// ---------------- K2c: rel-V context, contiguous streaming ----------------
__global__ __launch_bounds__(256, 2) void k_relv(
    const unsigned short* __restrict__ pbf,   // [B][H][L][R] bf16
    const float* __restrict__ relv,           // [B][R][L][D] f32
    unsigned short* __restrict__ part) {      // [4 rc][B][L][768] bf16
  __shared__ __align__(16) char PS[49152];    // P [12][16][128] bf16 swizzled
  const int tid = threadIdx.x, lane = tid & 63, w = tid >> 6;
  const int lg = blockIdx.x, rc = blockIdx.y, b = blockIdx.z;
  const int l0 = lg * 16, r0 = rc * 128;

  {
    const int x = tid & 15, rowb = tid >> 4;
#pragma unroll
    for (int pass = 0; pass < 12; ++pass) {
      const int ri = pass * 16 + rowb;
      const int h = ri >> 4, lr = ri & 15;
      const char* src = (const char*)pbf +
          ((((size_t)b * 12 + h) * 512 + l0 + lr) * 512 + r0) * 2 + (size_t)x * 16;
      u32x4 v = *(const u32x4*)src;
      *(u32x4*)(PS + h * 4096 + lr * 256 + ((x * 16) ^ ((lr & 3) << 4))) = v;
    }
  }
  __syncthreads();

  const int lr_w = w * 4 + (lane >> 4);
  const int l = l0 + lr_w;
  const char* rvb = (const char*)relv +
      (((size_t)b * 512 + r0) * 512 + l) * 256 + (size_t)(lane & 15) * 16;

  f32x4 vA[8], vB[8], vC[8];
  f32x4 acc[12];
#pragma unroll
  for (int h = 0; h < 12; ++h) acc[h] = {0.f, 0.f, 0.f, 0.f};

#define VISSUE(o, buf)                                                        \
  do {                                                                        \
    GL16(buf[0], rvb + (size_t)((o) * 8 + 0) * 131072, 0);                    \
    GL16(buf[1], rvb + (size_t)((o) * 8 + 1) * 131072, 0);                    \
    GL16(buf[2], rvb + (size_t)((o) * 8 + 2) * 131072, 0);                    \
    GL16(buf[3], rvb + (size_t)((o) * 8 + 3) * 131072, 0);                    \
    GL16(buf[4], rvb + (size_t)((o) * 8 + 4) * 131072, 0);                    \
    GL16(buf[5], rvb + (size_t)((o) * 8 + 5) * 131072, 0);                    \
    GL16(buf[6], rvb + (size_t)((o) * 8 + 6) * 131072, 0);                    \
    GL16(buf[7], rvb + (size_t)((o) * 8 + 7) * 131072, 0);                    \
  } while (0)
#define VCONS(o, buf)                                                         \
  do {                                                                        \
    _Pragma("unroll")                                                         \
    for (int h = 0; h < 12; ++h) {                                            \
      bf16x8 p8 = *(const bf16x8*)(PS + h * 4096 + lr_w * 256 +               \
                                   (((o) * 16) ^ ((lr_w & 3) << 4)));         \
      _Pragma("unroll")                                                       \
      for (int j = 0; j < 8; ++j) {                                           \
        const float pf = bf2f((unsigned short)p8[j]);                         \
        acc[h] += pf * buf[j];                                                \
      }                                                                       \
    }                                                                         \
  } while (0)

  VISSUE(0, vA);
  VISSUE(1, vB);
  VISSUE(2, vC);
  WAITV(16); VCONS(0, vA);  VISSUE(3, vA);
  WAITV(16); VCONS(1, vB);  VISSUE(4, vB);
  WAITV(16); VCONS(2, vC);  VISSUE(5, vC);
  WAITV(16); VCONS(3, vA);  VISSUE(6, vA);
  WAITV(16); VCONS(4, vB);  VISSUE(7, vB);
  WAITV(16); VCONS(5, vC);  VISSUE(8, vC);
  WAITV(16); VCONS(6, vA);  VISSUE(9, vA);
  WAITV(16); VCONS(7, vB);  VISSUE(10, vB);
  WAITV(16); VCONS(8, vC);  VISSUE(11, vC);
  WAITV(16); VCONS(9, vA);  VISSUE(12, vA);
  WAITV(16); VCONS(10, vB); VISSUE(13, vB);
  WAITV(16); VCONS(11, vC); VISSUE(14, vC);
  WAITV(16); VCONS(12, vA); VISSUE(15, vA);
  WAITV(16); VCONS(13, vB);
  WAITV(8);  VCONS(14, vC);
  WAITV(0);  VCONS(15, vA);
#undef VISSUE
#undef VCONS

  unsigned short* op = part + ((size_t)rc * 2048 + (size_t)b * 512 + l) * 768 + (lane & 15) * 4;
#pragma unroll
  for (int h = 0; h < 12; ++h) {
    u32x2 pk;
    pk.x = cvtpk(acc[h][0], acc[h][1]);
    pk.y = cvtpk(acc[h][2], acc[h][3]);
    *(u32x2*)(op + h * 64) = pk;
  }
}

// ---------------- K3: ctx = P@V per (b,h) via MFMA, + 4 bf16 partials -----
__global__ __launch_bounds__(256) void k_pv(
    const unsigned short* __restrict__ pbf, const unsigned short* __restrict__ vbt,
    const unsigned short* __restrict__ part, float* __restrict__ out) {
  __shared__ __align__(16) unsigned short lP[64 * 64];
  __shared__ __align__(16) unsigned short lV[64 * 64];
  const int tid = threadIdx.x, lane = tid & 63, w = tid >> 6;
  const int lt = blockIdx.x, bh = blockIdx.y;
  const int b = bh / 12, h = bh % 12;
  const int wm = (w >> 1) * 32, wn = (w & 1) * 32;
  f32x4 acc[2][2] = {};
  const char* pbase = (const char*)pbf + ((size_t)bh * 512 + lt * 64) * 1024;
  const char* vbase = (const char*)vbt + (size_t)bh * 64 * 1024;
  for (int kt = 0; kt < 8; ++kt) {
    __syncthreads();
#pragma unroll
    for (int i = 0; i < 2; ++i) {
      int e16 = i * 256 + tid;
      int row = e16 >> 3;
      int kb = (e16 & 7) * 16;
      int dst = row * 128 + (kb ^ ((row & 7) << 4));
      u32x4 vp = *(const u32x4*)(pbase + (size_t)row * 1024 + kt * 128 + kb);
      *(u32x4*)((char*)lP + dst) = vp;
      u32x4 vv = *(const u32x4*)(vbase + (size_t)row * 1024 + kt * 128 + kb);
      *(u32x4*)((char*)lV + dst) = vv;
    }
    __syncthreads();
#pragma unroll
    for (int ks = 0; ks < 2; ++ks) {
      bf16x8 fa[2], fb[2];
      const int kbyte = (ks * 32 + (lane >> 4) * 8) * 2;
#pragma unroll
      for (int mi = 0; mi < 2; ++mi) {
        int row = wm + mi * 16 + (lane & 15);
        fa[mi] = *(const bf16x8*)((const char*)lP + row * 128 + (kbyte ^ ((row & 7) << 4)));
      }
#pragma unroll
      for (int ni = 0; ni < 2; ++ni) {
        int row = wn + ni * 16 + (lane & 15);
        fb[ni] = *(const bf16x8*)((const char*)lV + row * 128 + (kbyte ^ ((row & 7) << 4)));
      }
#pragma unroll
      for (int mi = 0; mi < 2; ++mi)
#pragma unroll
        for (int ni = 0; ni < 2; ++ni)
          acc[mi][ni] = __builtin_amdgcn_mfma_f32_16x16x32_bf16(fa[mi], fb[ni], acc[mi][ni], 0, 0, 0);
    }
  }
#pragma unroll
  for (int mi = 0; mi < 2; ++mi)
#pragma unroll
    for (int ni = 0; ni < 2; ++ni) {
      int gd = wn + ni * 16 + (lane & 15);
#pragma unroll
      for (int r = 0; r < 4; ++r) {
        int gl = lt * 64 + wm + mi * 16 + ((lane >> 4) << 2) + r;
        size_t o = ((size_t)b * 512 + gl) * 768 + h * 64 + gd;
        out[o] = acc[mi][ni][r] + bf2f(part[o]) + bf2f(part[o + 1572864]) +
                 bf2f(part[o + 3145728]) + bf2f(part[o + 4718592]);
      }
    }
}

extern "C" void kernel_launch(void* const* d_in, const int* in_sizes, int n_in,
                              void* d_out, int out_size, void* d_ws, size_t ws_size,
                              hipStream_t stream) {
  (void)in_sizes; (void)n_in; (void)out_size; (void)ws_size;
  const float* hidden = (const float*)d_in[0];
  const float* relk   = (const float*)d_in[1];
  const float* relv   = (const float*)d_in[2];
  const float* Wq     = (const float*)d_in[3];
  const float* bq     = (const float*)d_in[4];
  const float* Wk     = (const float*)d_in[5];
  const float* bk     = (const float*)d_in[6];
  const float* Wv     = (const float*)d_in[7];
  const float* bv     = (const float*)d_in[8];
  float* out = (float*)d_out;
  char* ws = (char*)d_ws;

  unsigned short* hb  = (unsigned short*)(ws);
  unsigned short* wt  = (unsigned short*)(ws + 3145728);
  unsigned short* qbf = (unsigned short*)(ws + 6684672);
  unsigned short* kbf = (unsigned short*)(ws + 9830400);
  unsigned short* vbt = (unsigned short*)(ws + 12976128);
  unsigned short* Sb  = (unsigned short*)(ws + 16121856);  // dead after k_relA
  unsigned short* part= (unsigned short*)(ws + 16121856);  // 12.6 MB overlay
  unsigned short* pbf = (unsigned short*)(ws + 66453504);

  k_prep<<<1968, 256, 0, stream>>>(hidden, Wq, Wk, Wv, hb, wt);
  k_qkv_gemm<<<dim3(32, 36), 256, 0, stream>>>(hb, wt, bq, bk, bv, qbf, kbf, vbt);
  k_scores<<<dim3(8, 8, 48), 256, 0, stream>>>(qbf, kbf, Sb);
  k_relA<<<2048, 256, 0, stream>>>(qbf, relk, Sb, pbf);
  k_relv<<<dim3(32, 4, 4), 256, 0, stream>>>(pbf, relv, part);
  k_pv<<<dim3(8, 48), 256, 0, stream>>>(pbf, vbt, part, out);
}